// Round 1
// baseline (95.160 us; speedup 1.0000x reference)
//
#include <hip/hip_runtime.h>

// Problem constants (from reference): MAXK=51, MINK=5 -> NK=11, PAD=4, EXTRA=2
// B=16, C_OUT=64, N_REP=4, C_IN=704, HIN=68, HOUT=64. SHIFTS[i] = 21 - 5*i.
constexpr int NKc    = 11;
constexpr int C_OUTc = 64;
constexpr int N_REPc = 4;
constexpr int HINc   = 68;
constexpr int HOUTc  = 64;
constexpr int LSTR   = 72;     // padded LDS row stride (floats)
constexpr int CH_ELEMS = HINc * HINc;        // 4624
constexpr int CH_F4    = CH_ELEMS / 4;       // 1156

typedef float f4 __attribute__((ext_vector_type(4)));

__global__ __launch_bounds__(256, 4) void lora_fused(
    const float* __restrict__ in,
    const int* __restrict__ idx1,
    const int* __restrict__ idx2,
    const int* __restrict__ idxs,
    float* __restrict__ out)
{
    const int b    = blockIdx.x >> 6;   // 16 batches
    const int co   = blockIdx.x & 63;   // 64 output channels
    const int tid  = threadIdx.x;
    const int lane = tid & 63;          // output column w
    const int wv   = tid >> 6;          // wave id -> row block
    const int h0   = wv * 16;           // this wave owns output rows h0..h0+15

    __shared__ float ldsF[HINc * LSTR];       // one 68x68 channel, padded stride 72
    __shared__ float w1f[NKc * NKc];
    __shared__ float w2f[NKc * NKc];
    __shared__ float wsf[NKc];

    // ---- build per-(co) weight tables: w[i][j] = #r with perm(r,i)==j ----
    if (tid < NKc * NKc) { w1f[tid] = 0.f; w2f[tid] = 0.f; }
    if (tid < NKc) wsf[tid] = 0.f;
    __syncthreads();
    if (tid < N_REPc * NKc) {
        int r = tid / NKc, i = tid - r * NKc;
        int j = idx1[r * (C_OUTc * NKc) + co * NKc + i] - co * NKc;
        atomicAdd(&w1f[i * NKc + j], 1.f);
    } else if (tid >= 64 && tid < 64 + N_REPc * NKc) {
        int t = tid - 64;
        int r = t / NKc, i = t - r * NKc;
        int j = idx2[r * (C_OUTc * NKc) + co * NKc + i] - co * NKc;
        atomicAdd(&w2f[i * NKc + j], 1.f);
    } else if (tid >= 128 && tid < 128 + N_REPc) {
        int r = tid - 128;
        int j = idxs[r * C_OUTc + co] - co * NKc;
        atomicAdd(&wsf[j], 1.f);
    }
    // (first __syncthreads inside the j-loop orders these before any weight read)

    float acc1[16], acc2[16], accS[16];
    #pragma unroll
    for (int k = 0; k < 16; ++k) { acc1[k] = 0.f; acc2[k] = 0.f; accS[k] = 0.f; }

    const float* chbase = in + (size_t)(b * (C_OUTc * NKc) + co * NKc) * CH_ELEMS;

    for (int j = 0; j < NKc; ++j) {
        __syncthreads();   // previous iteration's reads done / weights built
        // ---- stage channel j (68x68) into padded LDS, coalesced float4 ----
        const f4* src = (const f4*)(chbase + j * CH_ELEMS);
        #pragma unroll
        for (int it = 0; it < 5; ++it) {
            int t = tid + it * 256;
            if (t < CH_F4) {
                f4 v = __builtin_nontemporal_load(&src[t]);   // streamed, no reuse
                int flat = t * 4;
                int r = flat / HINc;
                int c = flat - r * HINc;                       // multiple of 4
                *(f4*)&ldsF[r * LSTR + c] = v;
            }
        }
        __syncthreads();

        // ---- lora1: shift along h. hh validity is wave-uniform -> scalar skip
        #pragma unroll 1
        for (int i = 0; i < NKc; ++i) {
            float wt = w1f[i * NKc + j];
            if (wt == 0.f) continue;
            int dh = 5 * i - 21 + h0;
            #pragma unroll
            for (int k = 0; k < 16; ++k) {
                int hh = dh + k;
                if ((unsigned)hh < (unsigned)HINc)
                    acc1[k] = fmaf(wt, ldsF[hh * LSTR + lane + 2], acc1[k]);
            }
        }
        // ---- lora2: shift along w. column validity is per-lane (predicated)
        #pragma unroll 1
        for (int i = 0; i < NKc; ++i) {
            float wt = w2f[i * NKc + j];
            if (wt == 0.f) continue;
            int ww = lane + 5 * i - 21;
            if ((unsigned)ww < (unsigned)HINc) {
                #pragma unroll
                for (int k = 0; k < 16; ++k)
                    acc2[k] = fmaf(wt, ldsF[(h0 + k + 2) * LSTR + ww], acc2[k]);
            }
        }
        // ---- small: plain crop-accumulate
        {
            float wt = wsf[j];
            if (wt != 0.f) {
                #pragma unroll
                for (int k = 0; k < 16; ++k)
                    accS[k] = fmaf(wt, ldsF[(h0 + k + 2) * LSTR + lane + 2], accS[k]);
            }
        }
    }

    // ---- write the three output tensors (contiguous per-wave rows, coalesced)
    const int tens = 16 * C_OUTc * HOUTc * HOUTc;   // 4194304 elements per tensor
    float* o1 = out + (size_t)(b * C_OUTc + co) * (HOUTc * HOUTc);
    #pragma unroll
    for (int k = 0; k < 16; ++k) {
        int off = (h0 + k) * HOUTc + lane;
        __builtin_nontemporal_store(acc1[k], &o1[off]);
        __builtin_nontemporal_store(acc2[k], &o1[tens + off]);
        __builtin_nontemporal_store(accS[k], &o1[2 * tens + off]);
    }
}

extern "C" void kernel_launch(void* const* d_in, const int* in_sizes, int n_in,
                              void* d_out, int out_size, void* d_ws, size_t ws_size,
                              hipStream_t stream) {
    const float* in   = (const float*)d_in[0];
    const int*   idx1 = (const int*)d_in[1];
    const int*   idx2 = (const int*)d_in[2];
    const int*   idxs = (const int*)d_in[3];
    float* o = (float*)d_out;
    // grid: one block per (b, co) pair = 16*64 = 1024 blocks
    lora_fused<<<dim3(16 * C_OUTc), dim3(256), 0, stream>>>(in, idx1, idx2, idxs, o);
}

// Round 2
// 42.599 us; speedup vs baseline: 2.2339x; 2.2339x over previous
//
#include <hip/hip_runtime.h>

// Problem constants: MAXK=51, MINK=5 -> NK=11, PAD=4, EXTRA=2
// B=16, C_OUT=64, N_REP=4, C_IN=704, HIN=68, HOUT=64. shift(i) = 5i-21 (input row/col offset).
constexpr int NKc    = 11;
constexpr int C_OUTc = 64;
constexpr int N_REPc = 4;
constexpr int HINc   = 68;
constexpr int HOUTc  = 64;
constexpr int CH     = HINc * HINc;   // 4624 floats per channel
constexpr int CH16   = CH / 4;        // 1156 16-byte chunks

#define GAS(p) ((const __attribute__((address_space(1))) void*)(p))
#define LAS(p) ((__attribute__((address_space(3))) void*)(p))

// Stage one 68x68 channel (18.5 KB) global->LDS, async, linear layout.
__device__ __forceinline__ void stage_ch(const float* __restrict__ src, float* dst, int tid) {
    #pragma unroll
    for (int it = 0; it < 5; ++it) {
        int t = it * 256 + tid;
        if (t < CH16)
            __builtin_amdgcn_global_load_lds(GAS(src + t * 4), LAS(dst + t * 4), 16, 0, 0);
    }
}

template <int H0>
__device__ __forceinline__ void run_rows(
    const float* __restrict__ chbase,   // global base of this (b,co) group's 11 channels
    float* __restrict__ buf0, float* __restrict__ buf1,
    const float* __restrict__ w1f, const float* __restrict__ w2f, const float* __restrict__ wsf,
    int tid, int lane, float* __restrict__ o1)
{
    float acc1[16], acc2[16], accS[16];
    #pragma unroll
    for (int k = 0; k < 16; ++k) { acc1[k] = 0.f; acc2[k] = 0.f; accS[k] = 0.f; }

    const float* cur = buf0;
    float* nxt = buf1;

    for (int j = 0; j < NKc; ++j) {
        // Issue next channel's async loads first; they complete during compute.
        if (j + 1 < NKc) stage_ch(chbase + (j + 1) * CH, nxt, tid);

        // Batch all weight loads for this j (independent LDS reads, pipelined).
        float wt1[NKc], wt2[NKc];
        #pragma unroll
        for (int i = 0; i < NKc; ++i) { wt1[i] = w1f[i * NKc + j]; wt2[i] = w2f[i * NKc + j]; }
        float wts = wsf[j];

        // ---- lora1: row shifts; bounds are compile-time via H0 ----
        #pragma unroll
        for (int i = 0; i < NKc; ++i) {
            if (wt1[i] != 0.f) {                 // wave-uniform runtime branch
                const int dh = 5 * i - 21 + H0;  // compile-time after unroll
                #pragma unroll
                for (int k = 0; k < 16; ++k) {
                    if (dh + k >= 0 && dh + k < HINc)   // folds at compile time
                        acc1[k] = fmaf(wt1[i], cur[(dh + k) * HINc + lane + 2], acc1[k]);
                }
            }
        }
        // ---- lora2: column shifts; per-lane validity hoisted out of k-loop ----
        #pragma unroll
        for (int i = 0; i < NKc; ++i) {
            if (wt2[i] != 0.f) {
                int ww = lane + 5 * i - 21;
                if ((unsigned)ww < (unsigned)HINc) {
                    #pragma unroll
                    for (int k = 0; k < 16; ++k)
                        acc2[k] = fmaf(wt2[i], cur[(H0 + k + 2) * HINc + ww], acc2[k]);
                }
            }
        }
        // ---- small: crop-accumulate ----
        if (wts != 0.f) {
            #pragma unroll
            for (int k = 0; k < 16; ++k)
                accS[k] = fmaf(wts, cur[(H0 + k + 2) * HINc + lane + 2], accS[k]);
        }

        __syncthreads();   // drains async loads (nxt ready) + orders reads before restage
        const float* t = cur; cur = nxt; nxt = (float*)t;
    }

    // ---- coalesced nontemporal stores ----
    const int tens = 16 * C_OUTc * HOUTc * HOUTc;
    #pragma unroll
    for (int k = 0; k < 16; ++k) {
        int off = (H0 + k) * HOUTc + lane;
        __builtin_nontemporal_store(acc1[k], &o1[off]);
        __builtin_nontemporal_store(acc2[k], &o1[tens + off]);
        __builtin_nontemporal_store(accS[k], &o1[2 * tens + off]);
    }
}

__global__ __launch_bounds__(256, 4) void lora_fused(
    const float* __restrict__ in,
    const int* __restrict__ idx1,
    const int* __restrict__ idx2,
    const int* __restrict__ idxs,
    float* __restrict__ out)
{
    const int b    = blockIdx.x >> 6;
    const int co   = blockIdx.x & 63;
    const int tid  = threadIdx.x;
    const int lane = tid & 63;
    const int wv   = tid >> 6;

    __shared__ float buf0[CH];
    __shared__ float buf1[CH];
    __shared__ float w1f[NKc * NKc];
    __shared__ float w2f[NKc * NKc];
    __shared__ float wsf[NKc];

    // ---- build per-co weight tables: w[i][j] = #r with perm(r,i)==j ----
    if (tid < NKc * NKc) { w1f[tid] = 0.f; w2f[tid] = 0.f; }
    if (tid < NKc) wsf[tid] = 0.f;
    __syncthreads();
    if (tid < N_REPc * NKc) {
        int r = tid / NKc, i = tid - r * NKc;
        int j = idx1[r * (C_OUTc * NKc) + co * NKc + i] - co * NKc;
        atomicAdd(&w1f[i * NKc + j], 1.f);
    } else if (tid >= 64 && tid < 64 + N_REPc * NKc) {
        int t = tid - 64;
        int r = t / NKc, i = t - r * NKc;
        int j = idx2[r * (C_OUTc * NKc) + co * NKc + i] - co * NKc;
        atomicAdd(&w2f[i * NKc + j], 1.f);
    } else if (tid >= 128 && tid < 128 + N_REPc) {
        int r = tid - 128;
        int j = idxs[r * C_OUTc + co] - co * NKc;
        atomicAdd(&wsf[j], 1.f);
    }

    const float* chbase = in + (size_t)(b * (C_OUTc * NKc) + co * NKc) * CH;
    stage_ch(chbase, buf0, tid);     // prologue: stage channel 0
    __syncthreads();                 // tables built + buf0 resident

    float* o1 = out + (size_t)(b * C_OUTc + co) * (HOUTc * HOUTc);
    switch (wv) {
        case 0: run_rows<0 >(chbase, buf0, buf1, w1f, w2f, wsf, tid, lane, o1); break;
        case 1: run_rows<16>(chbase, buf0, buf1, w1f, w2f, wsf, tid, lane, o1); break;
        case 2: run_rows<32>(chbase, buf0, buf1, w1f, w2f, wsf, tid, lane, o1); break;
        default: run_rows<48>(chbase, buf0, buf1, w1f, w2f, wsf, tid, lane, o1); break;
    }
}

extern "C" void kernel_launch(void* const* d_in, const int* in_sizes, int n_in,
                              void* d_out, int out_size, void* d_ws, size_t ws_size,
                              hipStream_t stream) {
    const float* in   = (const float*)d_in[0];
    const int*   idx1 = (const int*)d_in[1];
    const int*   idx2 = (const int*)d_in[2];
    const int*   idxs = (const int*)d_in[3];
    float* o = (float*)d_out;
    lora_fused<<<dim3(16 * C_OUTc), dim3(256), 0, stream>>>(in, idx1, idx2, idxs, o);
}